// Round 5
// baseline (176.282 us; speedup 1.0000x reference)
//
#include <hip/hip_runtime.h>
#include <math.h>

constexpr int NB = 8, NS = 2048, ND = 65;
constexpr int KP = 104;     // padded K stride for x conv (bf16 elems)
constexpr int VD = 80;      // padded d rows for V^T
constexpr size_t OUTSZ = (size_t)NB * NS * ND;
constexpr size_t CONVN = (size_t)NB * NS * KP;   // x conv elems per array
constexpr size_t VTN   = (size_t)NB * VD * NS;   // V^T elems per array

typedef short short8 __attribute__((ext_vector_type(8)));
typedef float f32x4 __attribute__((ext_vector_type(4)));

__device__ __forceinline__ ushort f2bf(float f) {
    uint u = __float_as_uint(f);
    return (ushort)((u + 0x7fffu + ((u >> 16) & 1u)) >> 16);   // RNE
}
__device__ __forceinline__ float bf2f(ushort h) {
    return __uint_as_float((uint)h << 16);
}

// ---------------------------------------------------------------------------
// k0x: x fp32 -> (hi, lo) bf16 split arrays, K padded 65->104 with zeros.
// ---------------------------------------------------------------------------
__global__ __launch_bounds__(256)
void k0_convert(const float* __restrict__ x, ushort* __restrict__ xhi,
                ushort* __restrict__ xlo)
{
    size_t i = (size_t)blockIdx.x * 256 + threadIdx.x;
    if (i >= CONVN) return;
    int d = (int)(i % KP);
    size_t row = i / KP;
    ushort h = 0, l = 0;
    if (d < ND) {
        float v = x[row * ND + d];
        h = f2bf(v);
        l = f2bf(v - bf2f(h));
    }
    xhi[i] = h; xlo[i] = l;
}

// ---------------------------------------------------------------------------
// k0v: V [b,t,d] fp32 -> V^T hi/lo bf16 [b, d(80, zero-pad), t(2048)]
// ---------------------------------------------------------------------------
__global__ __launch_bounds__(256)
void k0v_transpose(const float* __restrict__ v, ushort* __restrict__ vthi,
                   ushort* __restrict__ vtlo)
{
    __shared__ float sT[128][66];
    const int tid = threadIdx.x, b = blockIdx.y, t0 = blockIdx.x * 128;
    const float* vb = v + (size_t)b * NS * ND;
    for (int i = tid; i < 128 * ND; i += 256) {
        int t = i / ND, d = i - t * ND;
        sT[t][d] = vb[(size_t)(t0 + t) * ND + d];
    }
    __syncthreads();
    for (int i = tid; i < VD * 128; i += 256) {
        int d = i >> 7, t = i & 127;
        float val = (d < ND) ? sT[t][d] : 0.0f;
        ushort h = f2bf(val);
        ushort l = f2bf(val - bf2f(h));
        size_t o = ((size_t)b * VD + d) * NS + t0 + t;
        vthi[o] = h; vtlo[o] = l;
    }
}

// ---------------------------------------------------------------------------
// k1: per (batch, 64-row block): S via split-bf16 MFMA (hi*hi+hi*lo+lo*hi),
// E = exp(-acosh(clip)/T) written fp32 unnormalized, inv[row] -> ws.
// TC=128 col tiles, double-buffered sB with reg staging (loads issued before
// compute, ds_write after barrier) so staging latency hides under compute.
// ---------------------------------------------------------------------------
__global__ __launch_bounds__(512, 1)
void k1_scores(const ushort* __restrict__ xhi, const ushort* __restrict__ xlo,
               const float* __restrict__ tptr, float* __restrict__ attn,
               float* __restrict__ invb)
{
    __shared__ __align__(16) ushort sAh[64 * KP], sAl[64 * KP];
    __shared__ __align__(16) ushort sBh[2][128 * KP], sBl[2][128 * KP];
    __shared__ float sSum[4][64];

    const int tid = threadIdx.x;
    const int b  = blockIdx.y;
    const int r0 = blockIdx.x * 64;
    const int lane = tid & 63;
    const int w  = tid >> 6;
    const int wr = w >> 2;          // 0..1  (32-row slab)
    const int wc = w & 3;           // 0..3  (32-col slab)
    const float invT = 1.0f / (tptr[0] + 1e-8f);

    const ushort* xhb = xhi + (size_t)b * NS * KP;
    const ushort* xlb = xlo + (size_t)b * NS * KP;
    float* arow = attn + ((size_t)b * NS + r0) * NS;

    // stage A rows (64 x KP, hi+lo)
    {
        const uint4* sh = (const uint4*)(xhb + (size_t)r0 * KP);
        const uint4* sl = (const uint4*)(xlb + (size_t)r0 * KP);
        uint4* dh = (uint4*)sAh; uint4* dl = (uint4*)sAl;
        for (int i = tid; i < 64 * KP / 8; i += 512) { dh[i] = sh[i]; dl[i] = sl[i]; }
    }

    // prologue: load B tile 0 into regs
    constexpr int NB4 = 128 * KP / 8;   // 1664 uint4 per array
    uint4 rh[4], rl[4];
    {
        const uint4* gh = (const uint4*)xhb;
        const uint4* gl = (const uint4*)xlb;
        #pragma unroll
        for (int i = 0; i < 4; ++i) {
            int idx = tid + i * 512;
            if (idx < NB4) { rh[i] = gh[idx]; rl[i] = gl[idx]; }
        }
    }
    __syncthreads();
    if (tid < 64) { sAh[tid * KP] ^= 0x8000; sAl[tid * KP] ^= 0x8000; }  // negate time dim
    {
        uint4* dh = (uint4*)sBh[0]; uint4* dl = (uint4*)sBl[0];
        #pragma unroll
        for (int i = 0; i < 4; ++i) {
            int idx = tid + i * 512;
            if (idx < NB4) { dh[idx] = rh[i]; dl[idx] = rl[i]; }
        }
    }
    __syncthreads();

    float rsum[2][4];
    #pragma unroll
    for (int rf = 0; rf < 2; ++rf)
        #pragma unroll
        for (int j = 0; j < 4; ++j) rsum[rf][j] = 0.0f;

    for (int t = 0; t < 16; ++t) {
        const int cur = t & 1;
        const int tc = t * 128;

        if (t < 15) {   // issue next tile's loads (latency hides under compute)
            const uint4* gh = (const uint4*)(xhb + (size_t)(tc + 128) * KP);
            const uint4* gl = (const uint4*)(xlb + (size_t)(tc + 128) * KP);
            #pragma unroll
            for (int i = 0; i < 4; ++i) {
                int idx = tid + i * 512;
                if (idx < NB4) { rh[i] = gh[idx]; rl[i] = gl[idx]; }
            }
        }

        // ---- compute tile t from buf[cur] ----
        f32x4 acc[2][2];
        #pragma unroll
        for (int rf = 0; rf < 2; ++rf)
            #pragma unroll
            for (int cf = 0; cf < 2; ++cf)
                #pragma unroll
                for (int j = 0; j < 4; ++j) acc[rf][cf][j] = 0.0f;

        #pragma unroll
        for (int kc = 0; kc < 3; ++kc) {
            const int koff = kc * 32 + (lane >> 4) * 8;
            short8 ah[2], al[2], bh[2], bl[2];
            #pragma unroll
            for (int rf = 0; rf < 2; ++rf) {
                int ro = (wr * 32 + rf * 16 + (lane & 15)) * KP + koff;
                ah[rf] = *(const short8*)&sAh[ro];
                al[rf] = *(const short8*)&sAl[ro];
            }
            #pragma unroll
            for (int cf = 0; cf < 2; ++cf) {
                int co = (wc * 32 + cf * 16 + (lane & 15)) * KP + koff;
                bh[cf] = *(const short8*)&sBh[cur][co];
                bl[cf] = *(const short8*)&sBl[cur][co];
            }
            #pragma unroll
            for (int rf = 0; rf < 2; ++rf)
                #pragma unroll
                for (int cf = 0; cf < 2; ++cf) {
                    acc[rf][cf] = __builtin_amdgcn_mfma_f32_16x16x32_bf16(ah[rf], bh[cf], acc[rf][cf], 0, 0, 0);
                    acc[rf][cf] = __builtin_amdgcn_mfma_f32_16x16x32_bf16(ah[rf], bl[cf], acc[rf][cf], 0, 0, 0);
                    acc[rf][cf] = __builtin_amdgcn_mfma_f32_16x16x32_bf16(al[rf], bh[cf], acc[rf][cf], 0, 0, 0);
                }
        }

        #pragma unroll
        for (int rf = 0; rf < 2; ++rf)
            #pragma unroll
            for (int cf = 0; cf < 2; ++cf)
                #pragma unroll
                for (int j = 0; j < 4; ++j) {
                    float z = -acc[rf][cf][j];
                    z = fminf(fmaxf(z, 1.0000001f), 50.0f);
                    float dist = __logf(z + __fsqrt_rn(z * z - 1.0f));
                    float e = __expf(-dist * invT);
                    int row = wr * 32 + rf * 16 + (lane >> 4) * 4 + j;
                    int col = tc + wc * 32 + cf * 16 + (lane & 15);
                    arow[(size_t)row * NS + col] = e;
                    rsum[rf][j] += e;
                }

        __syncthreads();   // all waves done reading buf[cur]... and buf[cur^1] from t-1
        if (t < 15) {
            uint4* dh = (uint4*)sBh[cur ^ 1]; uint4* dl = (uint4*)sBl[cur ^ 1];
            #pragma unroll
            for (int i = 0; i < 4; ++i) {
                int idx = tid + i * 512;
                if (idx < NB4) { dh[idx] = rh[i]; dl[idx] = rl[i]; }
            }
        }
        __syncthreads();
    }

    // deterministic row-sum reduce: 16 lanes (lane&15) share each row
    #pragma unroll
    for (int rf = 0; rf < 2; ++rf)
        #pragma unroll
        for (int j = 0; j < 4; ++j) {
            float v = rsum[rf][j];
            v += __shfl_xor(v, 1, 64);
            v += __shfl_xor(v, 2, 64);
            v += __shfl_xor(v, 4, 64);
            v += __shfl_xor(v, 8, 64);
            if ((lane & 15) == 0)
                sSum[wc][wr * 32 + rf * 16 + (lane >> 4) * 4 + j] = v;
        }
    __syncthreads();
    if (tid < 64)
        invb[(size_t)b * NS + r0 + tid] =
            1.0f / (sSum[0][tid] + sSum[1][tid] + sSum[2][tid] + sSum[3][tid]);
}

// ---------------------------------------------------------------------------
// k2: per (batch, 32-row block): read E tile (L3-hot), normalize, write attn
// in place, split to bf16 in LDS; stage V^T chunk [80][128] hi/lo into LDS
// (coalesced), MFMA PV with 4 waves k-slicing the 128-chunk. Partial O
// reduced via LDS buffer aliasing the dead sV region (keeps 2 blocks/CU).
// ---------------------------------------------------------------------------
__global__ __launch_bounds__(256, 2)
void k2_pv(float* __restrict__ attn, const ushort* __restrict__ vthi,
           const ushort* __restrict__ vtlo, const float* __restrict__ invb,
           float* __restrict__ out)
{
    // manual LDS layout: sA (32x136 hi/lo) + sV (80x136 hi/lo); sRed aliases sV
    __shared__ __align__(16) char smem[(32 * 136 * 2 + 80 * 136 * 2) * 2];
    ushort* sAh = (ushort*)smem;            // 32*136
    ushort* sAl = sAh + 32 * 136;
    ushort* sVh = sAl + 32 * 136;           // 80*136
    ushort* sVl = sVh + 80 * 136;
    float*  sRed = (float*)(sAl + 32 * 136);   // 4*32*80 f32 = 40960B <= 43520B
    __shared__ float sInvL[32];

    const int tid = threadIdx.x;
    const int b  = blockIdx.y;
    const int r0 = blockIdx.x * 32;
    const int lane = tid & 63;
    const int wk = tid >> 6;          // k-slice 0..3 within each 128-chunk

    if (tid < 32) sInvL[tid] = invb[(size_t)b * NS + r0 + tid];

    float* arow = attn + ((size_t)b * NS + r0) * NS;
    const ushort* vh = vthi + (size_t)b * VD * NS;
    const ushort* vl = vtlo + (size_t)b * VD * NS;

    f32x4 acc[2][5];
    #pragma unroll
    for (int rf = 0; rf < 2; ++rf)
        #pragma unroll
        for (int f = 0; f < 5; ++f)
            #pragma unroll
            for (int j = 0; j < 4; ++j) acc[rf][f][j] = 0.0f;

    __syncthreads();

    for (int kt = 0; kt < NS; kt += 128) {
        // stage E: 32 rows x 32 float4; RMW normalize + bf16 split into sA
        #pragma unroll
        for (int rep = 0; rep < 4; ++rep) {
            int idx = tid + rep * 256;
            int row = idx >> 5, c4 = idx & 31;
            float4* p = (float4*)&arow[(size_t)row * NS + kt + c4 * 4];
            float4 e = *p;
            float inv = sInvL[row];
            e.x *= inv; e.y *= inv; e.z *= inv; e.w *= inv;
            *p = e;
            ushort h0 = f2bf(e.x), h1 = f2bf(e.y), h2 = f2bf(e.z), h3 = f2bf(e.w);
            ushort l0 = f2bf(e.x - bf2f(h0)), l1 = f2bf(e.y - bf2f(h1));
            ushort l2 = f2bf(e.z - bf2f(h2)), l3 = f2bf(e.w - bf2f(h3));
            int so = row * 136 + c4 * 4;
            *(ushort4*)&sAh[so] = make_ushort4(h0, h1, h2, h3);
            *(ushort4*)&sAl[so] = make_ushort4(l0, l1, l2, l3);
        }
        // stage V^T chunk [80][128] hi/lo: coalesced 16B/lane rows
        #pragma unroll
        for (int rep = 0; rep < 5; ++rep) {
            int i = tid + rep * 256;
            int d = i >> 4, c8 = i & 15;
            size_t go = (size_t)d * NS + kt + c8 * 8;
            *(short8*)&sVh[d * 136 + c8 * 8] = *(const short8*)&vh[go];
            *(short8*)&sVl[d * 136 + c8 * 8] = *(const short8*)&vl[go];
        }
        __syncthreads();

        const int koff = wk * 32 + (lane >> 4) * 8;
        short8 ah[2], al[2];
        #pragma unroll
        for (int rf = 0; rf < 2; ++rf) {
            int ro = (rf * 16 + (lane & 15)) * 136 + koff;
            ah[rf] = *(const short8*)&sAh[ro];
            al[rf] = *(const short8*)&sAl[ro];
        }
        #pragma unroll
        for (int f = 0; f < 5; ++f) {
            int vo = (f * 16 + (lane & 15)) * 136 + koff;
            short8 bh = *(const short8*)&sVh[vo];
            short8 bl = *(const short8*)&sVl[vo];
            #pragma unroll
            for (int rf = 0; rf < 2; ++rf) {
                acc[rf][f] = __builtin_amdgcn_mfma_f32_16x16x32_bf16(ah[rf], bh, acc[rf][f], 0, 0, 0);
                acc[rf][f] = __builtin_amdgcn_mfma_f32_16x16x32_bf16(ah[rf], bl, acc[rf][f], 0, 0, 0);
                acc[rf][f] = __builtin_amdgcn_mfma_f32_16x16x32_bf16(al[rf], bh, acc[rf][f], 0, 0, 0);
            }
        }
        __syncthreads();   // protect sA/sV rewrite next chunk
    }

    // write k-slice partials into sRed (aliases dead sV region)
    #pragma unroll
    for (int rf = 0; rf < 2; ++rf)
        #pragma unroll
        for (int f = 0; f < 5; ++f)
            #pragma unroll
            for (int j = 0; j < 4; ++j) {
                int r = rf * 16 + (lane >> 4) * 4 + j;
                int d = f * 16 + (lane & 15);
                sRed[((size_t)wk * 32 + r) * 80 + d] = acc[rf][f][j];
            }
    __syncthreads();
    for (int i = tid; i < 32 * 80; i += 256) {
        int r = i / 80, d = i - r * 80;
        float s = sRed[(size_t)r * 80 + d] + sRed[(size_t)(32 + r) * 80 + d]
                + sRed[(size_t)(64 + r) * 80 + d] + sRed[(size_t)(96 + r) * 80 + d];
        if (d < ND) out[((size_t)b * NS + r0 + r) * ND + d] = s;
    }
}

extern "C" void kernel_launch(void* const* d_in, const int* in_sizes, int n_in,
                              void* d_out, int out_size, void* d_ws, size_t ws_size,
                              hipStream_t stream) {
    const float* x      = (const float*)d_in[0];
    const float* values = (const float*)d_in[1];
    const float* temp   = (const float*)d_in[2];

    float* out  = (float*)d_out;
    float* attn = out + OUTSZ;

    ushort* xhi  = (ushort*)d_ws;
    ushort* xlo  = xhi + CONVN;
    ushort* vthi = xlo + CONVN;
    ushort* vtlo = vthi + VTN;
    float*  invb = (float*)(vtlo + VTN);

    k0_convert<<<(int)((CONVN + 255) / 256), 256, 0, stream>>>(x, xhi, xlo);
    k0v_transpose<<<dim3(NS / 128, NB), 256, 0, stream>>>(values, vthi, vtlo);

    k1_scores<<<dim3(NS / 64, NB), 512, 0, stream>>>(xhi, xlo, temp, attn, invb);
    k2_pv<<<dim3(NS / 32, NB), 256, 0, stream>>>(attn, vthi, vtlo, invb, out);
}

// Round 6
// 139.368 us; speedup vs baseline: 1.2649x; 1.2649x over previous
//
#include <hip/hip_runtime.h>
#include <math.h>

constexpr int NB = 8, NS = 2048, ND = 65;
constexpr int KP = 104;     // padded K stride for x conv (bf16 elems)
constexpr int VD = 80;      // padded d rows for V^T
constexpr size_t OUTSZ = (size_t)NB * NS * ND;
constexpr size_t CONVN = (size_t)NB * NS * KP;   // x conv elems per array
constexpr size_t VTN   = (size_t)NB * VD * NS;   // V^T elems per array

typedef short short8 __attribute__((ext_vector_type(8)));
typedef float f32x4 __attribute__((ext_vector_type(4)));

__device__ __forceinline__ ushort f2bf(float f) {
    uint u = __float_as_uint(f);
    return (ushort)((u + 0x7fffu + ((u >> 16) & 1u)) >> 16);   // RNE
}
__device__ __forceinline__ float bf2f(ushort h) {
    return __uint_as_float((uint)h << 16);
}

// ---------------------------------------------------------------------------
// k0x: x fp32 -> (hi, lo) bf16 split arrays, K padded 65->104 with zeros.
// ---------------------------------------------------------------------------
__global__ __launch_bounds__(256)
void k0_convert(const float* __restrict__ x, ushort* __restrict__ xhi,
                ushort* __restrict__ xlo)
{
    size_t i = (size_t)blockIdx.x * 256 + threadIdx.x;
    if (i >= CONVN) return;
    int d = (int)(i % KP);
    size_t row = i / KP;
    ushort h = 0, l = 0;
    if (d < ND) {
        float v = x[row * ND + d];
        h = f2bf(v);
        l = f2bf(v - bf2f(h));
    }
    xhi[i] = h; xlo[i] = l;
}

// ---------------------------------------------------------------------------
// k0v: V [b,t,d] fp32 -> V^T hi/lo bf16 [b, d(80, zero-pad), t(2048)]
// ---------------------------------------------------------------------------
__global__ __launch_bounds__(256)
void k0v_transpose(const float* __restrict__ v, ushort* __restrict__ vthi,
                   ushort* __restrict__ vtlo)
{
    __shared__ float sT[128][66];
    const int tid = threadIdx.x, b = blockIdx.y, t0 = blockIdx.x * 128;
    const float* vb = v + (size_t)b * NS * ND;
    for (int i = tid; i < 128 * ND; i += 256) {
        int t = i / ND, d = i - t * ND;
        sT[t][d] = vb[(size_t)(t0 + t) * ND + d];
    }
    __syncthreads();
    for (int i = tid; i < VD * 128; i += 256) {
        int d = i >> 7, t = i & 127;
        float val = (d < ND) ? sT[t][d] : 0.0f;
        ushort h = f2bf(val);
        ushort l = f2bf(val - bf2f(h));
        size_t o = ((size_t)b * VD + d) * NS + t0 + t;
        vthi[o] = h; vtlo[o] = l;
    }
}

// ---------------------------------------------------------------------------
// k1 (reverted to the proven r3/r4 structure, ~63us): per (batch, 64-row
// block): S via split-bf16 MFMA (hi*hi + hi*lo + lo*hi), E = exp(-acosh/T)
// written fp32 unnormalized, inv[row] -> ws. TC=256, single-buffered.
// Scores in [-4.61, -4.5e-4] => exp without max-subtract == softmax exactly.
// ---------------------------------------------------------------------------
__global__ __launch_bounds__(512, 1)
void k1_scores(const ushort* __restrict__ xhi, const ushort* __restrict__ xlo,
               const float* __restrict__ tptr, float* __restrict__ attn,
               float* __restrict__ invb)
{
    __shared__ __align__(16) ushort sAh[64 * KP], sAl[64 * KP];
    __shared__ __align__(16) ushort sBh[256 * KP], sBl[256 * KP];
    __shared__ float sSum[4][64];

    const int tid = threadIdx.x;
    const int b  = blockIdx.y;
    const int r0 = blockIdx.x * 64;
    const int lane = tid & 63;
    const int w  = tid >> 6;
    const int wr = w >> 2;          // 0..1  (32-row slab)
    const int wc = w & 3;           // 0..3  (64-col slab)
    const float invT = 1.0f / (tptr[0] + 1e-8f);

    const ushort* xhb = xhi + (size_t)b * NS * KP;
    const ushort* xlb = xlo + (size_t)b * NS * KP;
    float* arow = attn + ((size_t)b * NS + r0) * NS;

    {
        const uint4* sh = (const uint4*)(xhb + (size_t)r0 * KP);
        const uint4* sl = (const uint4*)(xlb + (size_t)r0 * KP);
        uint4* dh = (uint4*)sAh; uint4* dl = (uint4*)sAl;
        for (int i = tid; i < 64 * KP / 8; i += 512) { dh[i] = sh[i]; dl[i] = sl[i]; }
    }
    __syncthreads();
    if (tid < 64) { sAh[tid * KP] ^= 0x8000; sAl[tid * KP] ^= 0x8000; }  // negate time dim

    float rsum[2][4];
    #pragma unroll
    for (int rf = 0; rf < 2; ++rf)
        #pragma unroll
        for (int j = 0; j < 4; ++j) rsum[rf][j] = 0.0f;

    for (int tc = 0; tc < NS; tc += 256) {
        __syncthreads();
        {
            const uint4* sh = (const uint4*)(xhb + (size_t)tc * KP);
            const uint4* sl = (const uint4*)(xlb + (size_t)tc * KP);
            uint4* dh = (uint4*)sBh; uint4* dl = (uint4*)sBl;
            for (int i = tid; i < 256 * KP / 8; i += 512) { dh[i] = sh[i]; dl[i] = sl[i]; }
        }
        __syncthreads();

        f32x4 acc[2][4];
        #pragma unroll
        for (int rf = 0; rf < 2; ++rf)
            #pragma unroll
            for (int cf = 0; cf < 4; ++cf)
                #pragma unroll
                for (int j = 0; j < 4; ++j) acc[rf][cf][j] = 0.0f;

        #pragma unroll
        for (int kc = 0; kc < 3; ++kc) {
            const int koff = kc * 32 + (lane >> 4) * 8;
            short8 ah[2], al[2], bh[4], bl[4];
            #pragma unroll
            for (int rf = 0; rf < 2; ++rf) {
                int ro = (wr * 32 + rf * 16 + (lane & 15)) * KP + koff;
                ah[rf] = *(const short8*)&sAh[ro];
                al[rf] = *(const short8*)&sAl[ro];
            }
            #pragma unroll
            for (int cf = 0; cf < 4; ++cf) {
                int co = (wc * 64 + cf * 16 + (lane & 15)) * KP + koff;
                bh[cf] = *(const short8*)&sBh[co];
                bl[cf] = *(const short8*)&sBl[co];
            }
            #pragma unroll
            for (int rf = 0; rf < 2; ++rf)
                #pragma unroll
                for (int cf = 0; cf < 4; ++cf) {
                    acc[rf][cf] = __builtin_amdgcn_mfma_f32_16x16x32_bf16(ah[rf], bh[cf], acc[rf][cf], 0, 0, 0);
                    acc[rf][cf] = __builtin_amdgcn_mfma_f32_16x16x32_bf16(ah[rf], bl[cf], acc[rf][cf], 0, 0, 0);
                    acc[rf][cf] = __builtin_amdgcn_mfma_f32_16x16x32_bf16(al[rf], bh[cf], acc[rf][cf], 0, 0, 0);
                }
        }

        #pragma unroll
        for (int rf = 0; rf < 2; ++rf)
            #pragma unroll
            for (int cf = 0; cf < 4; ++cf)
                #pragma unroll
                for (int j = 0; j < 4; ++j) {
                    float z = -acc[rf][cf][j];
                    z = fminf(fmaxf(z, 1.0000001f), 50.0f);
                    float dist = __logf(z + __fsqrt_rn(z * z - 1.0f));
                    float e = __expf(-dist * invT);
                    int row = wr * 32 + rf * 16 + (lane >> 4) * 4 + j;
                    int col = tc + wc * 64 + cf * 16 + (lane & 15);
                    arow[(size_t)row * NS + col] = e;
                    rsum[rf][j] += e;
                }
    }

    // deterministic row-sum reduce: 16 lanes (lane&15) share each row
    #pragma unroll
    for (int rf = 0; rf < 2; ++rf)
        #pragma unroll
        for (int j = 0; j < 4; ++j) {
            float v = rsum[rf][j];
            v += __shfl_xor(v, 1, 64);
            v += __shfl_xor(v, 2, 64);
            v += __shfl_xor(v, 4, 64);
            v += __shfl_xor(v, 8, 64);
            if ((lane & 15) == 0)
                sSum[wc][wr * 32 + rf * 16 + (lane >> 4) * 4 + j] = v;
        }
    __syncthreads();
    if (tid < 64)
        invb[(size_t)b * NS + r0 + tid] =
            1.0f / (sSum[0][tid] + sSum[1][tid] + sSum[2][tid] + sSum[3][tid]);
}

// ---------------------------------------------------------------------------
// k2 (kept from r5, ~60us): per (batch, 32-row block): read E tile (L3-hot),
// normalize, write attn in place, split to bf16 in LDS; stage V^T chunk
// [80][128] hi/lo into LDS (coalesced), MFMA PV, 4 waves k-slicing; partial O
// reduced via LDS buffer aliasing the dead sV region (2 blocks/CU).
// ---------------------------------------------------------------------------
__global__ __launch_bounds__(256, 2)
void k2_pv(float* __restrict__ attn, const ushort* __restrict__ vthi,
           const ushort* __restrict__ vtlo, const float* __restrict__ invb,
           float* __restrict__ out)
{
    __shared__ __align__(16) char smem[(32 * 136 * 2 + 80 * 136 * 2) * 2];
    ushort* sAh = (ushort*)smem;            // 32*136
    ushort* sAl = sAh + 32 * 136;
    ushort* sVh = sAl + 32 * 136;           // 80*136
    ushort* sVl = sVh + 80 * 136;
    float*  sRed = (float*)(sAl + 32 * 136);   // 4*32*80 f32 aliases sV
    __shared__ float sInvL[32];

    const int tid = threadIdx.x;
    const int b  = blockIdx.y;
    const int r0 = blockIdx.x * 32;
    const int lane = tid & 63;
    const int wk = tid >> 6;          // k-slice 0..3 within each 128-chunk

    if (tid < 32) sInvL[tid] = invb[(size_t)b * NS + r0 + tid];

    float* arow = attn + ((size_t)b * NS + r0) * NS;
    const ushort* vh = vthi + (size_t)b * VD * NS;
    const ushort* vl = vtlo + (size_t)b * VD * NS;

    f32x4 acc[2][5];
    #pragma unroll
    for (int rf = 0; rf < 2; ++rf)
        #pragma unroll
        for (int f = 0; f < 5; ++f)
            #pragma unroll
            for (int j = 0; j < 4; ++j) acc[rf][f][j] = 0.0f;

    __syncthreads();

    for (int kt = 0; kt < NS; kt += 128) {
        // stage E: 32 rows x 32 float4; RMW normalize + bf16 split into sA
        #pragma unroll
        for (int rep = 0; rep < 4; ++rep) {
            int idx = tid + rep * 256;
            int row = idx >> 5, c4 = idx & 31;
            float4* p = (float4*)&arow[(size_t)row * NS + kt + c4 * 4];
            float4 e = *p;
            float inv = sInvL[row];
            e.x *= inv; e.y *= inv; e.z *= inv; e.w *= inv;
            *p = e;
            ushort h0 = f2bf(e.x), h1 = f2bf(e.y), h2 = f2bf(e.z), h3 = f2bf(e.w);
            ushort l0 = f2bf(e.x - bf2f(h0)), l1 = f2bf(e.y - bf2f(h1));
            ushort l2 = f2bf(e.z - bf2f(h2)), l3 = f2bf(e.w - bf2f(h3));
            int so = row * 136 + c4 * 4;
            *(ushort4*)&sAh[so] = make_ushort4(h0, h1, h2, h3);
            *(ushort4*)&sAl[so] = make_ushort4(l0, l1, l2, l3);
        }
        // stage V^T chunk [80][128] hi/lo: coalesced 16B/lane rows
        #pragma unroll
        for (int rep = 0; rep < 5; ++rep) {
            int i = tid + rep * 256;
            int d = i >> 4, c8 = i & 15;
            size_t go = (size_t)d * NS + kt + c8 * 8;
            *(short8*)&sVh[d * 136 + c8 * 8] = *(const short8*)&vh[go];
            *(short8*)&sVl[d * 136 + c8 * 8] = *(const short8*)&vl[go];
        }
        __syncthreads();

        const int koff = wk * 32 + (lane >> 4) * 8;
        short8 ah[2], al[2];
        #pragma unroll
        for (int rf = 0; rf < 2; ++rf) {
            int ro = (rf * 16 + (lane & 15)) * 136 + koff;
            ah[rf] = *(const short8*)&sAh[ro];
            al[rf] = *(const short8*)&sAl[ro];
        }
        #pragma unroll
        for (int f = 0; f < 5; ++f) {
            int vo = (f * 16 + (lane & 15)) * 136 + koff;
            short8 bh = *(const short8*)&sVh[vo];
            short8 bl = *(const short8*)&sVl[vo];
            #pragma unroll
            for (int rf = 0; rf < 2; ++rf) {
                acc[rf][f] = __builtin_amdgcn_mfma_f32_16x16x32_bf16(ah[rf], bh, acc[rf][f], 0, 0, 0);
                acc[rf][f] = __builtin_amdgcn_mfma_f32_16x16x32_bf16(ah[rf], bl, acc[rf][f], 0, 0, 0);
                acc[rf][f] = __builtin_amdgcn_mfma_f32_16x16x32_bf16(al[rf], bh, acc[rf][f], 0, 0, 0);
            }
        }
        __syncthreads();   // protect sA/sV rewrite next chunk
    }

    // write k-slice partials into sRed (aliases dead sV region)
    #pragma unroll
    for (int rf = 0; rf < 2; ++rf)
        #pragma unroll
        for (int f = 0; f < 5; ++f)
            #pragma unroll
            for (int j = 0; j < 4; ++j) {
                int r = rf * 16 + (lane >> 4) * 4 + j;
                int d = f * 16 + (lane & 15);
                sRed[((size_t)wk * 32 + r) * 80 + d] = acc[rf][f][j];
            }
    __syncthreads();
    for (int i = tid; i < 32 * 80; i += 256) {
        int r = i / 80, d = i - r * 80;
        float s = sRed[(size_t)r * 80 + d] + sRed[(size_t)(32 + r) * 80 + d]
                + sRed[(size_t)(64 + r) * 80 + d] + sRed[(size_t)(96 + r) * 80 + d];
        if (d < ND) out[((size_t)b * NS + r0 + r) * ND + d] = s;
    }
}

extern "C" void kernel_launch(void* const* d_in, const int* in_sizes, int n_in,
                              void* d_out, int out_size, void* d_ws, size_t ws_size,
                              hipStream_t stream) {
    const float* x      = (const float*)d_in[0];
    const float* values = (const float*)d_in[1];
    const float* temp   = (const float*)d_in[2];

    float* out  = (float*)d_out;
    float* attn = out + OUTSZ;

    ushort* xhi  = (ushort*)d_ws;
    ushort* xlo  = xhi + CONVN;
    ushort* vthi = xlo + CONVN;
    ushort* vtlo = vthi + VTN;
    float*  invb = (float*)(vtlo + VTN);

    k0_convert<<<(int)((CONVN + 255) / 256), 256, 0, stream>>>(x, xhi, xlo);
    k0v_transpose<<<dim3(NS / 128, NB), 256, 0, stream>>>(values, vthi, vtlo);

    k1_scores<<<dim3(NS / 64, NB), 512, 0, stream>>>(xhi, xlo, temp, attn, invb);
    k2_pv<<<dim3(NS / 32, NB), 256, 0, stream>>>(attn, vthi, vtlo, invb, out);
}